// Round 8
// baseline (129.494 us; speedup 1.0000x reference)
//
#include <hip/hip_runtime.h>
#include <hip/hip_bf16.h>

typedef __attribute__((ext_vector_type(8))) short short8;
typedef __attribute__((ext_vector_type(4))) float f32x4;
using bf16 = __hip_bfloat16;

__device__ __forceinline__ unsigned short f2bf(float f) {
    unsigned u = __float_as_uint(f);
    u += 0x7fff + ((u >> 16) & 1);           // round-to-nearest-even
    return (unsigned short)(u >> 16);
}
__device__ __forceinline__ float bf2f(unsigned short s) {
    return __uint_as_float(((unsigned)s) << 16);
}
// async global->LDS DMA, 16B/lane; global lane addrs CONTIGUOUS (packed layout)
__device__ __forceinline__ void gl_lds16(const unsigned short* g, unsigned short* l) {
    __builtin_amdgcn_global_load_lds(
        (const __attribute__((address_space(1))) unsigned int*)g,
        (__attribute__((address_space(3))) unsigned int*)l, 16, 0, 0);
}

// Packed LDS cell layout (shorts): cell = (sl*64 + r)*8 + el  (sl = k/8, el = k%8)
// fragment read for MFMA = contiguous 16B per (row, k-slice) -- proven since R0.

// ---------------------------------------------------------------- QKV GEMM, f32-direct (pack fused in)
// Tile 64(m) x 64(n) x 3z, BK=64, single LDS buffer, reg-staged conversion (pack_kernel's exact math).
// Loads for tile it+1 issue before compute of tile it (latency overlap). Grid (64,8)=512 blocks.
__global__ __launch_bounds__(256) void qkv_gemm_kernel(
    const float* __restrict__ X,
    const float* __restrict__ W0, const float* __restrict__ W1, const float* __restrict__ W2,
    const float* __restrict__ b0, const float* __restrict__ b1, const float* __restrict__ b2,
    bf16* __restrict__ O0, bf16* __restrict__ O1, bf16* __restrict__ O2,
    float* __restrict__ ssq)
{
    __shared__ __align__(16) unsigned short smem[16384];   // A 4096 + B0/B1/B2 4096 each = 32KB
    int g = blockIdx.x, gy = blockIdx.y;
    int m0 = g * 64, n0 = gy * 64;
    int tid = threadIdx.x;
    int lane = tid & 63;
    int w = tid >> 6;
    int wm = (w >> 1) * 32;
    int wn = (w & 1) * 32;
    int fr = lane & 15, qf = lane >> 4;
    (void)lane;

    // staging assignment (identical to pack_kernel): row sr = tid>>2, k-quarter skq = tid&3
    int sr = tid >> 2, skq = tid & 3;
    const float* xrow = X  + (size_t)(m0 + sr) * 512 + skq * 16;
    const float* w0r  = W0 + (size_t)(n0 + sr) * 512 + skq * 16;
    const float* w1r  = W1 + (size_t)(n0 + sr) * 512 + skq * 16;
    const float* w2r  = W2 + (size_t)(n0 + sr) * 512 + skq * 16;

    f32x4 zero4 = {0.f, 0.f, 0.f, 0.f};
    f32x4 acc[3][2][2];
    #pragma unroll
    for (int z = 0; z < 3; ++z)
        #pragma unroll
        for (int t = 0; t < 2; ++t)
            #pragma unroll
            for (int u = 0; u < 2; ++u) acc[z][t][u] = zero4;

    float4 a4[4], g0[4], g1[4], g2[4];
#define QKV_LOAD(k0) do {                                           \
        _Pragma("unroll")                                           \
        for (int i = 0; i < 4; ++i) {                               \
            a4[i] = *(const float4*)(xrow + (k0) + i * 4);          \
            g0[i] = *(const float4*)(w0r  + (k0) + i * 4);          \
            g1[i] = *(const float4*)(w1r  + (k0) + i * 4);          \
            g2[i] = *(const float4*)(w2r  + (k0) + i * 4);          \
        }                                                           \
    } while (0)

    QKV_LOAD(0);
    for (int it = 0; it < 8; ++it) {
        __syncthreads();                       // previous compute done reading LDS
        #pragma unroll
        for (int i = 0; i < 4; ++i) {          // cvt + write (pack_kernel's cell math)
            int kk = skq * 16 + i * 4;
            int sl = kk >> 3, el = kk & 7;
            int cell = (sl * 64 + sr) * 8 + el;
            ushort4 ua, u0, u1, u2;
            ua.x = f2bf(a4[i].x); ua.y = f2bf(a4[i].y); ua.z = f2bf(a4[i].z); ua.w = f2bf(a4[i].w);
            u0.x = f2bf(g0[i].x); u0.y = f2bf(g0[i].y); u0.z = f2bf(g0[i].z); u0.w = f2bf(g0[i].w);
            u1.x = f2bf(g1[i].x); u1.y = f2bf(g1[i].y); u1.z = f2bf(g1[i].z); u1.w = f2bf(g1[i].w);
            u2.x = f2bf(g2[i].x); u2.y = f2bf(g2[i].y); u2.z = f2bf(g2[i].z); u2.w = f2bf(g2[i].w);
            *(ushort4*)&smem[cell]         = ua;
            *(ushort4*)&smem[4096  + cell] = u0;
            *(ushort4*)&smem[8192  + cell] = u1;
            *(ushort4*)&smem[12288 + cell] = u2;
        }
        if (it < 7) QKV_LOAD((it + 1) * 64);   // in flight during compute below
        __syncthreads();
        #pragma unroll
        for (int kk = 0; kk < 2; ++kk) {
            int ks = (kk * 4 + qf) * 64;
            short8 af0 = *(const short8*)&smem[(ks + wm + fr) * 8];
            short8 af1 = *(const short8*)&smem[(ks + wm + 16 + fr) * 8];
            #pragma unroll
            for (int z = 0; z < 3; ++z) {
                const unsigned short* Bs = smem + 4096 + z * 4096;
                short8 bf0 = *(const short8*)&Bs[(ks + wn + fr) * 8];
                short8 bf1 = *(const short8*)&Bs[(ks + wn + 16 + fr) * 8];
                acc[z][0][0] = __builtin_amdgcn_mfma_f32_16x16x32_bf16(af0, bf0, acc[z][0][0], 0, 0, 0);
                acc[z][0][1] = __builtin_amdgcn_mfma_f32_16x16x32_bf16(af0, bf1, acc[z][0][1], 0, 0, 0);
                acc[z][1][0] = __builtin_amdgcn_mfma_f32_16x16x32_bf16(af1, bf0, acc[z][1][0], 0, 0, 0);
                acc[z][1][1] = __builtin_amdgcn_mfma_f32_16x16x32_bf16(af1, bf1, acc[z][1][1], 0, 0, 0);
            }
        }
    }
#undef QKV_LOAD

    int rb = qf * 4;
    #pragma unroll
    for (int z = 0; z < 3; ++z) {
        const float* bias = (z == 0) ? b0 : ((z == 1) ? b1 : b2);
        #pragma unroll
        for (int u = 0; u < 2; ++u) {
            float bv = bias[n0 + wn + u * 16 + fr];
            #pragma unroll
            for (int t = 0; t < 2; ++t)
                #pragma unroll
                for (int r = 0; r < 4; ++r) {
                    float v = acc[z][t][u][r] + bv;
                    if (z < 2) v = fmaxf(v, 0.f);
                    acc[z][t][u][r] = v;
                }
        }
    }
    #pragma unroll
    for (int z = 0; z < 2; ++z)
        #pragma unroll
        for (int t = 0; t < 2; ++t)
            #pragma unroll
            for (int r = 0; r < 4; ++r) {
                float s = acc[z][t][0][r] * acc[z][t][0][r] + acc[z][t][1][r] * acc[z][t][1][r];
                #pragma unroll
                for (int off = 1; off < 16; off <<= 1) s += __shfl_xor(s, off, 64);
                if (fr == 0) atomicAdd(&ssq[z * 4096 + m0 + wm + t * 16 + rb + r], s);
            }
    __syncthreads();                           // LDS dead -> stage all 3 C tiles (24KB)
    #pragma unroll
    for (int z = 0; z < 3; ++z)
        #pragma unroll
        for (int t = 0; t < 2; ++t)
            #pragma unroll
            for (int u = 0; u < 2; ++u)
                #pragma unroll
                for (int r = 0; r < 4; ++r)
                    smem[z * 4096 + (wm + t * 16 + rb + r) * 64 + wn + u * 16 + fr] = f2bf(acc[z][t][u][r]);
    __syncthreads();
    unsigned short* O0s = (unsigned short*)O0;
    unsigned short* O1s = (unsigned short*)O1;
    unsigned short* O2s = (unsigned short*)O2;
    #pragma unroll
    for (int rep = 0; rep < 6; ++rep) {
        int idx = rep * 256 + tid;            // 1536 uint4 = 3 x 64 x 64 shorts
        int z = idx >> 9, rem = idx & 511;
        int row = rem >> 3, col8 = (rem & 7) * 8;
        unsigned short* Oz = (z == 0) ? O0s : ((z == 1) ? O1s : O2s);
        *(uint4*)(Oz + (size_t)(m0 + row) * 512 + n0 + col8) = *(const uint4*)&smem[z * 4096 + row * 64 + col8];
    }
}

// ---------------------------------------------------------------- per-chunk (64 rows) KV sums (bf16 out) + scaled V^T
// ScT[(n*32+c)][m*64+d] bf16 = sum_{j in chunk c} k[j][d]*v'[j][m], v' = v/|k_row|
// Vt_g[n][m][l] = v'[l][m] bf16.   Grid 512 = (n 16, c 32) -> 2 blocks/CU.
__global__ __launch_bounds__(256) void chunk_kv_kernel(
    const bf16* __restrict__ Kb, const bf16* __restrict__ Vb,
    const float* __restrict__ ssq, bf16* __restrict__ ScT, bf16* __restrict__ Vt_g)
{
    int n = blockIdx.x >> 5, c = blockIdx.x & 31;
    int b = n >> 3, h = n & 7;
    __shared__ float Ks[64 * 64];
    __shared__ float Vs[64 * 64];
    const unsigned short* Kg = (const unsigned short*)Kb;
    const unsigned short* Vg = (const unsigned short*)Vb;
    int tid = threadIdx.x;
    int td = tid >> 4, tm = tid & 15;
    int d0 = td * 4, m0 = tm * 4;
    #pragma unroll
    for (int rep = 0; rep < 4; ++rep) {
        int idx = rep * 1024 + tid * 4;
        int j = idx >> 6, d = idx & 63;
        int grow = (c * 64 + j) * 2 + b;
        ushort4 ku = *(const ushort4*)&Kg[(size_t)grow * 512 + h * 64 + d];
        ushort4 vu = *(const ushort4*)&Vg[(size_t)grow * 512 + h * 64 + d];
        float rk = 1.f / fmaxf(sqrtf(ssq[4096 + grow]), 1e-12f);
        *(float4*)&Ks[j * 64 + d] = make_float4(bf2f(ku.x), bf2f(ku.y), bf2f(ku.z), bf2f(ku.w));
        *(float4*)&Vs[j * 64 + d] = make_float4(bf2f(vu.x) * rk, bf2f(vu.y) * rk,
                                                bf2f(vu.z) * rk, bf2f(vu.w) * rk);
    }
    __syncthreads();
    float acc[4][4] = {};
    for (int j = 0; j < 64; ++j) {
        float4 kv = *(const float4*)&Ks[j * 64 + d0];
        float4 vv = *(const float4*)&Vs[j * 64 + m0];
        acc[0][0] += kv.x*vv.x; acc[0][1] += kv.x*vv.y; acc[0][2] += kv.x*vv.z; acc[0][3] += kv.x*vv.w;
        acc[1][0] += kv.y*vv.x; acc[1][1] += kv.y*vv.y; acc[1][2] += kv.y*vv.z; acc[1][3] += kv.y*vv.w;
        acc[2][0] += kv.z*vv.x; acc[2][1] += kv.z*vv.y; acc[2][2] += kv.z*vv.z; acc[2][3] += kv.z*vv.w;
        acc[3][0] += kv.w*vv.x; acc[3][1] += kv.w*vv.y; acc[3][2] += kv.w*vv.z; acc[3][3] += kv.w*vv.w;
    }
    // scaled V^T bf16: thread -> m = tid&63, 16 j's starting at (tid>>6)*16
    int vm = tid & 63, vj0 = (tid >> 6) * 16;
    unsigned short tmp[16];
    #pragma unroll
    for (int i = 0; i < 16; ++i) tmp[i] = f2bf(Vs[(vj0 + i) * 64 + vm]);
    size_t vtoff = (size_t)n * 131072 + (size_t)vm * 2048 + c * 64 + vj0;
    *(uint4*)((unsigned short*)Vt_g + vtoff)     = *(uint4*)&tmp[0];
    *(uint4*)((unsigned short*)Vt_g + vtoff + 8) = *(uint4*)&tmp[8];

    unsigned short* outp = (unsigned short*)ScT + (size_t)blockIdx.x * 4096;  // plane [m][d] bf16
    #pragma unroll
    for (int j2 = 0; j2 < 4; ++j2) {
        ushort4 o4;
        o4.x = f2bf(acc[0][j2]); o4.y = f2bf(acc[1][j2]);
        o4.z = f2bf(acc[2][j2]); o4.w = f2bf(acc[3][j2]);
        *(ushort4*)&outp[(m0 + j2) * 64 + d0] = o4;
    }
}

// ---------------------------------------------------------------- exclusive chunk prefix (32 planes) bf16->bf16
// 65536 threads, one (n, idx) column each; loads independent -> TLP hides L3 latency (R0/R1-proven pattern).
__global__ __launch_bounds__(256) void prefix_kernel(const bf16* __restrict__ ScT, bf16* __restrict__ SpT)
{
    int n = blockIdx.x >> 4;
    int idx = ((blockIdx.x & 15) << 8) + threadIdx.x;   // 0..4095 within plane
    size_t base = (size_t)n * 131072 + idx;
    const unsigned short* sc = (const unsigned short*)ScT;
    unsigned short* sp = (unsigned short*)SpT;
    float run = 0.f;
    #pragma unroll
    for (int c = 0; c < 32; ++c) {
        size_t off = base + (size_t)c * 4096;
        sp[off] = f2bf(run);
        run += bf2f(sc[off]);
    }
}

// ---------------------------------------------------------------- MFMA causal linear attention per (head, 64-chunk)
// out[l] = (1/|q_l|) * [ q_l @ Sprev + sum_{j<=l in chunk} (q_l . k_j) v'_j ].  Grid 512 -> 2 blocks/CU.
// Output written in PACKED layout for oproj: group g' = c*2+b, r = l, s = h*8..h*8+7.
__global__ __launch_bounds__(256) void attn_kernel(
    const bf16* __restrict__ Qb, const bf16* __restrict__ Kb,
    const bf16* __restrict__ Vt_g, const bf16* __restrict__ SpT_g,
    const float* __restrict__ ssq, bf16* __restrict__ AOb)
{
    int n = blockIdx.x >> 5, c = blockIdx.x & 31;
    int b = n >> 3, h = n & 7;
    __shared__ __align__(16) unsigned short Qs[64 * 72];   // [l][d]
    __shared__ __align__(16) unsigned short Ks[64 * 72];   // [j][d]
    __shared__ __align__(16) unsigned short Vt[64 * 72];   // [m][j]
    __shared__ __align__(16) unsigned short Ps[4 * 16 * 40];
    int tid = threadIdx.x;
    int lane = tid & 63;
    int w = tid >> 6;
    int fr = lane & 15, q = lane >> 4;

    const unsigned short* Qg = (const unsigned short*)Qb;
    const unsigned short* Kg = (const unsigned short*)Kb;
    const unsigned short* Vg = (const unsigned short*)Vt_g;

    #pragma unroll
    for (int rep = 0; rep < 2; ++rep) {
        int idx = rep * 256 + tid;
        int l = idx >> 3, dc = (idx & 7) * 8;
        size_t goff = (size_t)((c * 64 + l) * 2 + b) * 512 + h * 64 + dc;
        *(uint4*)&Qs[l * 72 + dc] = *(const uint4*)(Qg + goff);
        *(uint4*)&Ks[l * 72 + dc] = *(const uint4*)(Kg + goff);
        int m = l, jc = dc;
        *(uint4*)&Vt[m * 72 + jc] =
            *(const uint4*)(Vg + (size_t)n * 131072 + (size_t)m * 2048 + c * 64 + jc);
    }
    __syncthreads();

    short8 qfr[2];
    #pragma unroll
    for (int kh = 0; kh < 2; ++kh)
        qfr[kh] = *(const short8*)&Qs[(w * 16 + fr) * 72 + kh * 32 + q * 8];

    f32x4 zero4 = {0.f, 0.f, 0.f, 0.f};
    f32x4 oacc[4];
    #pragma unroll
    for (int mt = 0; mt < 4; ++mt) oacc[mt] = zero4;

    // O = Q @ Sprev^T (one 64x64 bf16 plane, L2/L3-hot)
    const unsigned short* spg = (const unsigned short*)SpT_g + (size_t)blockIdx.x * 4096;
    #pragma unroll
    for (int mt = 0; mt < 4; ++mt) {
        #pragma unroll
        for (int kh = 0; kh < 2; ++kh) {
            short8 sf = *(const short8*)&spg[(mt * 16 + fr) * 64 + kh * 32 + q * 8];
            oacc[mt] = __builtin_amdgcn_mfma_f32_16x16x32_bf16(qfr[kh], sf, oacc[mt], 0, 0, 0);
        }
    }

    unsigned short* myPs = &Ps[w * 640];      // 16 x 40
    int rbase = q * 4;
    int njt = (w >> 1) + 1;                   // 32-wide j-tiles needed by this wave
    for (int jt = 0; jt < njt; ++jt) {        // wave-uniform; barrier-free
        f32x4 pacc[2];
        pacc[0] = zero4; pacc[1] = zero4;
        #pragma unroll
        for (int jt16 = 0; jt16 < 2; ++jt16) {
            #pragma unroll
            for (int kh = 0; kh < 2; ++kh) {
                short8 kf = *(const short8*)&Ks[(jt * 32 + jt16 * 16 + fr) * 72 + kh * 32 + q * 8];
                pacc[jt16] = __builtin_amdgcn_mfma_f32_16x16x32_bf16(qfr[kh], kf, pacc[jt16], 0, 0, 0);
            }
        }
        bool diag = (jt == njt - 1);
        int lloc = w * 16 + rbase;            // + r
        #pragma unroll
        for (int jt16 = 0; jt16 < 2; ++jt16)
            #pragma unroll
            for (int r = 0; r < 4; ++r) {
                int jl = jt * 32 + jt16 * 16 + fr;
                float pv = pacc[jt16][r];
                if (diag && jl > lloc + r) pv = 0.f;
                myPs[(rbase + r) * 40 + jt16 * 16 + fr] = f2bf(pv);
            }
        short8 pf = *(const short8*)&myPs[fr * 40 + q * 8];
        #pragma unroll
        for (int mt = 0; mt < 4; ++mt) {
            short8 vf = *(const short8*)&Vt[(mt * 16 + fr) * 72 + jt * 32 + q * 8];
            oacc[mt] = __builtin_amdgcn_mfma_f32_16x16x32_bf16(pf, vf, oacc[mt], 0, 0, 0);
        }
    }

    // scale rows by 1/|q_l|, stage, PACKED coalesced store
    float rqv[4];
    #pragma unroll
    for (int r = 0; r < 4; ++r) {
        int flat = (c * 64 + w * 16 + rbase + r) * 2 + b;
        rqv[r] = 1.f / fmaxf(sqrtf(ssq[flat]), 1e-12f);
    }
    __syncthreads();                          // Qs dead -> O staging [l][m] stride 64
    #pragma unroll
    for (int mt = 0; mt < 4; ++mt)
        #pragma unroll
        for (int r = 0; r < 4; ++r)
            Qs[(w * 16 + rbase + r) * 64 + mt * 16 + fr] = f2bf(oacc[mt][r] * rqv[r]);
    __syncthreads();
    // packed cell ((g'*64 + s)*64 + r)*8 with g' = c*2+b, r = l, s = h*8 + sl
    #pragma unroll
    for (int rep = 0; rep < 2; ++rep) {
        int idx8 = rep * 256 + tid;
        int sl = idx8 >> 6, l = idx8 & 63;
        *(uint4*)((unsigned short*)AOb +
                  (size_t)(((c * 2 + b) * 64 + h * 8 + sl) * 64 + l) * 8) =
            *(const uint4*)&Qs[l * 64 + sl * 8];
    }
}

// ---------------------------------------------------------------- output projection: 64x64 tile, grid (64,8)=512
// A (packed bf16, from attn) via global_load_lds; Wo f32 reg-staged + converted inline (pack fused in).
__global__ __launch_bounds__(256) void oproj_kernel(
    const bf16* __restrict__ A, const float* __restrict__ Wo,
    const float* __restrict__ bias, float* __restrict__ Out)
{
    __shared__ __align__(16) unsigned short smem[8192];   // As 4096 + Bs 4096 = 16KB; epilogue Cf 64x64 f32
    const unsigned short* Ag = (const unsigned short*)A;
    unsigned short* As = smem;
    unsigned short* Bs = smem + 4096;
    int gp = blockIdx.x;              // packed A group
    int gy = blockIdx.y;
    int n0 = gy * 64;
    int tid = threadIdx.x;
    int lane = tid & 63;
    int w = tid >> 6;
    int fr = lane & 15, qf = lane >> 4;
    int wm = (w >> 1) * 32;
    int wn = (w & 1) * 32;
    int sr = tid >> 2, skq = tid & 3;
    const float* worow = Wo + (size_t)(n0 + sr) * 512 + skq * 16;

    f32x4 zero4 = {0.f, 0.f, 0.f, 0.f};
    f32x4 acc[2][2];
    acc[0][0] = zero4; acc[0][1] = zero4; acc[1][0] = zero4; acc[1][1] = zero4;

    for (int it = 0; it < 8; ++it) {
        int s0 = it * 8, k0 = it * 64;
        __syncthreads();                       // previous compute done reading LDS
        gl_lds16(Ag + ((size_t)(gp * 64 + s0 + w * 2)     * 64 + lane) * 8, As + w * 1024);
        gl_lds16(Ag + ((size_t)(gp * 64 + s0 + w * 2 + 1) * 64 + lane) * 8, As + w * 1024 + 512);
        #pragma unroll
        for (int i = 0; i < 4; ++i) {
            float4 v = *(const float4*)(worow + k0 + i * 4);
            int kk = skq * 16 + i * 4;
            int sl = kk >> 3, el = kk & 7;
            ushort4 u;
            u.x = f2bf(v.x); u.y = f2bf(v.y); u.z = f2bf(v.z); u.w = f2bf(v.w);
            *(ushort4*)&Bs[(sl * 64 + sr) * 8 + el] = u;
        }
        __syncthreads();                       // drains gl_lds (vmcnt0) + ds_writes
        #pragma unroll
        for (int kk = 0; kk < 2; ++kk) {
            short8 af[2], bfx[2];
            #pragma unroll
            for (int t = 0; t < 2; ++t)
                af[t] = *(const short8*)&As[((kk * 4 + qf) * 64 + wm + t * 16 + fr) * 8];
            #pragma unroll
            for (int u = 0; u < 2; ++u)
                bfx[u] = *(const short8*)&Bs[((kk * 4 + qf) * 64 + wn + u * 16 + fr) * 8];
            #pragma unroll
            for (int t = 0; t < 2; ++t)
                #pragma unroll
                for (int u = 0; u < 2; ++u)
                    acc[t][u] = __builtin_amdgcn_mfma_f32_16x16x32_bf16(af[t], bfx[u], acc[t][u], 0, 0, 0);
        }
    }

    int rb = qf * 4;
    float* Cf = (float*)smem;          // 64 x 64 fp32
    __syncthreads();                   // all LDS reads done before overwrite
    #pragma unroll
    for (int t = 0; t < 2; ++t)
        #pragma unroll
        for (int u = 0; u < 2; ++u) {
            float bv = bias[n0 + wn + u * 16 + fr];
            #pragma unroll
            for (int r = 0; r < 4; ++r)
                Cf[(wm + t * 16 + rb + r) * 64 + wn + u * 16 + fr] = acc[t][u][r] + bv;
        }
    __syncthreads();
    int cbase = (gp >> 1) * 128, bb = gp & 1;
    #pragma unroll
    for (int rep = 0; rep < 4; ++rep) {
        int idx = rep * 256 + tid;
        int l2 = idx >> 4, c4 = (idx & 15) * 4;
        *(float4*)(Out + (size_t)(cbase + l2 * 2 + bb) * 512 + n0 + c4) = *(const float4*)&Cf[l2 * 64 + c4];
    }
}

// ---------------------------------------------------------------- launch (5 kernels + ssq memset)
extern "C" void kernel_launch(void* const* d_in, const int* in_sizes, int n_in,
                              void* d_out, int out_size, void* d_ws, size_t ws_size,
                              hipStream_t stream)
{
    (void)in_sizes; (void)n_in; (void)out_size; (void)ws_size;
    const float* x  = (const float*)d_in[0];
    const float* Wq = (const float*)d_in[1];
    const float* bq = (const float*)d_in[2];
    const float* Wk = (const float*)d_in[3];
    const float* bk = (const float*)d_in[4];
    const float* Wv = (const float*)d_in[5];
    const float* bv = (const float*)d_in[6];
    const float* Wo = (const float*)d_in[7];
    const float* bo = (const float*)d_in[8];
    float* out = (float*)d_out;

    float* ssq = (float*)d_ws;            // 8192 f32
    bf16* Qb  = (bf16*)(ssq + 8192);      // row-major bf16 q/k/v, 4096x512 each
    bf16* Kb  = Qb + 2097152;
    bf16* Vb  = Kb + 2097152;
    bf16* Vt  = Vb + 2097152;             // 16*64*2048
    bf16* AOb = Vt + 2097152;             // PACKED attn output (g'=c*2+b, r=l)
    bf16* ScT = AOb + 2097152;            // 16*32*4096 bf16 chunk-sum planes [m][d]
    bf16* SpT = ScT + 2097152;            // 16*32*4096 bf16 exclusive-prefix planes

    hipMemsetAsync(ssq, 0, 8192 * sizeof(float), stream);
    qkv_gemm_kernel<<<dim3(64, 8), 256, 0, stream>>>(x, Wq, Wk, Wv, bq, bk, bv, Qb, Kb, Vb, ssq);
    chunk_kv_kernel<<<dim3(512), 256, 0, stream>>>(Kb, Vb, ssq, ScT, Vt);
    prefix_kernel<<<dim3(256), 256, 0, stream>>>(ScT, SpT);
    attn_kernel<<<dim3(512), 256, 0, stream>>>(Qb, Kb, Vt, SpT, ssq, AOb);
    oproj_kernel<<<dim3(64, 8), 256, 0, stream>>>(AOb, Wo, bo, out);
}

// Round 9
// 116.827 us; speedup vs baseline: 1.1084x; 1.1084x over previous
//
#include <hip/hip_runtime.h>
#include <hip/hip_bf16.h>

typedef __attribute__((ext_vector_type(8))) short short8;
typedef __attribute__((ext_vector_type(4))) float f32x4;
using bf16 = __hip_bfloat16;

__device__ __forceinline__ unsigned short f2bf(float f) {
    unsigned u = __float_as_uint(f);
    u += 0x7fff + ((u >> 16) & 1);           // round-to-nearest-even
    return (unsigned short)(u >> 16);
}
__device__ __forceinline__ float bf2f(unsigned short s) {
    return __uint_as_float(((unsigned)s) << 16);
}
// async global->LDS DMA, 16B/lane; global lane addrs CONTIGUOUS (packed layout)
__device__ __forceinline__ void gl_lds16(const unsigned short* g, unsigned short* l) {
    __builtin_amdgcn_global_load_lds(
        (const __attribute__((address_space(1))) unsigned int*)g,
        (__attribute__((address_space(3))) unsigned int*)l, 16, 0, 0);
}

// Packed layout (shorts): off = ((g*64 + s)*64 + r)*8   g=row/64, s=k/8, r=row%64
// => a wave staging (g, s, rows 0..63) reads 64 lanes x 16B = 1KB contiguous.

// ---------------------------------------------------------------- pack fp32 -> packed bf16 (+ zero ssq)
__global__ __launch_bounds__(256) void pack_kernel(
    const float* __restrict__ X, const float* __restrict__ Wq, const float* __restrict__ Wk,
    const float* __restrict__ Wv, const float* __restrict__ Wo,
    bf16* __restrict__ Xp, bf16* __restrict__ Wqp, bf16* __restrict__ Wkp,
    bf16* __restrict__ Wvp, bf16* __restrict__ Wop, float* __restrict__ ssq)
{
    __shared__ __align__(16) unsigned short sm[4096];   // [s_local 8][r 64][8]
    int id = blockIdx.x;
    int tid = threadIdx.x;
    if (id < 8) {
        int zi = id * 1024 + tid * 4;
        *(float4*)&ssq[zi] = make_float4(0.f, 0.f, 0.f, 0.f);
    }
    const float* src; unsigned short* dst; int g, sc;
    if (id < 512) { src = X; dst = (unsigned short*)Xp; g = id >> 3; sc = id & 7; }
    else {
        int t = id - 512; int wsel = t >> 6; int u = t & 63;
        g = u >> 3; sc = u & 7;
        src = (wsel == 0) ? Wq : ((wsel == 1) ? Wk : ((wsel == 2) ? Wv : Wo));
        dst = (unsigned short*)((wsel == 0) ? Wqp : ((wsel == 1) ? Wkp : ((wsel == 2) ? Wvp : Wop)));
    }
    int r = tid >> 2, kq = tid & 3;          // 64 rows x 4 k-chunks of 16
    const float* sp = src + (size_t)(g * 64 + r) * 512 + sc * 64 + kq * 16;
    #pragma unroll
    for (int i = 0; i < 4; ++i) {
        float4 v = *(const float4*)(sp + i * 4);
        int kk = kq * 16 + i * 4;            // local k 0..63
        int sl = kk >> 3, el = kk & 7;       // el in {0,4}
        ushort4 u4;
        u4.x = f2bf(v.x); u4.y = f2bf(v.y); u4.z = f2bf(v.z); u4.w = f2bf(v.w);
        *(ushort4*)&sm[(sl * 64 + r) * 8 + el] = u4;
    }
    __syncthreads();
    unsigned short* dp = dst + (size_t)g * 32768 + sc * 4096;   // 8 s-values contiguous
    *(uint4*)(dp + tid * 16)     = *(const uint4*)&sm[tid * 16];
    *(uint4*)(dp + tid * 16 + 8) = *(const uint4*)&sm[tid * 16 + 8];
}

// ---------------------------------------------------------------- QKV GEMM, z-FUSED (q,k,v in one block)
// Tile 64(m) x 64(n) x 3z, BK=64 double-buffered 2-phase. Grid (64,8) = 512 blocks, LDS 64KB -> 2 blocks/CU.
// Out(z) = act(x @ W(z)^T + b(z)) bf16; z<2 accumulates per-row sumsq (post-relu) into ssq[z*4096+row].
__global__ __launch_bounds__(256) void qkv_gemm_kernel(
    const bf16* __restrict__ Xp,
    const bf16* __restrict__ W0p, const bf16* __restrict__ W1p, const bf16* __restrict__ W2p,
    const float* __restrict__ b0, const float* __restrict__ b1, const float* __restrict__ b2,
    bf16* __restrict__ O0, bf16* __restrict__ O1, bf16* __restrict__ O2,
    float* __restrict__ ssq)
{
    // 64KB: 2 buffers x (A[8][64][8] 4096 + B0 4096 + B1 4096 + B2 4096)
    __shared__ __align__(16) unsigned short smem[32768];
    const unsigned short* Ag  = (const unsigned short*)Xp;
    const unsigned short* W0g = (const unsigned short*)W0p;
    const unsigned short* W1g = (const unsigned short*)W1p;
    const unsigned short* W2g = (const unsigned short*)W2p;
    int g = blockIdx.x, gy = blockIdx.y;
    int m0 = g * 64, n0 = gy * 64;
    int tid = threadIdx.x;
    int lane = tid & 63;
    int w = tid >> 6;
    int wm = (w >> 1) * 32;
    int wn = (w & 1) * 32;
    int fr = lane & 15, qf = lane >> 4;

    f32x4 zero4 = {0.f, 0.f, 0.f, 0.f};
    f32x4 acc[3][2][2];
    #pragma unroll
    for (int z = 0; z < 3; ++z)
        #pragma unroll
        for (int t = 0; t < 2; ++t)
            #pragma unroll
            for (int u = 0; u < 2; ++u) acc[z][t][u] = zero4;

    // stage one BK=64 tile: A 8 cells + 3x B 8 cells; 2 cells each per wave -> 8 gl_lds/wave
#define QKV_STAGE(buf, it) do {                                                              \
        unsigned short* bb = smem + (buf) * 16384;                                           \
        int s0_ = (it) * 8 + w * 2;                                                          \
        gl_lds16(Ag  + ((size_t)(g  * 64 + s0_)     * 64 + lane) * 8, bb + (w * 2)     * 512);        \
        gl_lds16(Ag  + ((size_t)(g  * 64 + s0_ + 1) * 64 + lane) * 8, bb + (w * 2 + 1) * 512);        \
        gl_lds16(W0g + ((size_t)(gy * 64 + s0_)     * 64 + lane) * 8, bb + 4096  + (w * 2)     * 512); \
        gl_lds16(W0g + ((size_t)(gy * 64 + s0_ + 1) * 64 + lane) * 8, bb + 4096  + (w * 2 + 1) * 512); \
        gl_lds16(W1g + ((size_t)(gy * 64 + s0_)     * 64 + lane) * 8, bb + 8192  + (w * 2)     * 512); \
        gl_lds16(W1g + ((size_t)(gy * 64 + s0_ + 1) * 64 + lane) * 8, bb + 8192  + (w * 2 + 1) * 512); \
        gl_lds16(W2g + ((size_t)(gy * 64 + s0_)     * 64 + lane) * 8, bb + 12288 + (w * 2)     * 512); \
        gl_lds16(W2g + ((size_t)(gy * 64 + s0_ + 1) * 64 + lane) * 8, bb + 12288 + (w * 2 + 1) * 512); \
    } while (0)

    int cur = 0;
    QKV_STAGE(0, 0);
    __syncthreads();
    for (int it = 0; it < 8; ++it) {
        if (it < 7) QKV_STAGE(cur ^ 1, it + 1);     // prefetch issues overlap compute
        const unsigned short* As = smem + cur * 16384;
        #pragma unroll
        for (int kk = 0; kk < 2; ++kk) {
            int ks = (kk * 4 + qf) * 64;
            short8 af[2];
            af[0] = *(const short8*)&As[(ks + wm + fr) * 8];
            af[1] = *(const short8*)&As[(ks + wm + 16 + fr) * 8];
            #pragma unroll
            for (int z = 0; z < 3; ++z) {
                const unsigned short* Bs = As + 4096 + z * 4096;
                short8 bf0 = *(const short8*)&Bs[(ks + wn + fr) * 8];
                short8 bf1 = *(const short8*)&Bs[(ks + wn + 16 + fr) * 8];
                acc[z][0][0] = __builtin_amdgcn_mfma_f32_16x16x32_bf16(af[0], bf0, acc[z][0][0], 0, 0, 0);
                acc[z][0][1] = __builtin_amdgcn_mfma_f32_16x16x32_bf16(af[0], bf1, acc[z][0][1], 0, 0, 0);
                acc[z][1][0] = __builtin_amdgcn_mfma_f32_16x16x32_bf16(af[1], bf0, acc[z][1][0], 0, 0, 0);
                acc[z][1][1] = __builtin_amdgcn_mfma_f32_16x16x32_bf16(af[1], bf1, acc[z][1][1], 0, 0, 0);
            }
        }
        __syncthreads();    // drains prefetch + guards buffer reuse; ONE barrier/iter
        cur ^= 1;
    }
#undef QKV_STAGE

    int rb = qf * 4;
    #pragma unroll
    for (int z = 0; z < 3; ++z) {
        const float* bias = (z == 0) ? b0 : ((z == 1) ? b1 : b2);
        #pragma unroll
        for (int u = 0; u < 2; ++u) {
            float bv = bias[n0 + wn + u * 16 + fr];
            #pragma unroll
            for (int t = 0; t < 2; ++t)
                #pragma unroll
                for (int r = 0; r < 4; ++r) {
                    float v = acc[z][t][u][r] + bv;
                    if (z < 2) v = fmaxf(v, 0.f);
                    acc[z][t][u][r] = v;
                }
        }
    }
    #pragma unroll
    for (int z = 0; z < 2; ++z)
        #pragma unroll
        for (int t = 0; t < 2; ++t)
            #pragma unroll
            for (int r = 0; r < 4; ++r) {
                float s = acc[z][t][0][r] * acc[z][t][0][r] + acc[z][t][1][r] * acc[z][t][1][r];
                #pragma unroll
                for (int off = 1; off < 16; off <<= 1) s += __shfl_xor(s, off, 64);
                if (fr == 0) atomicAdd(&ssq[z * 4096 + m0 + wm + t * 16 + rb + r], s);
            }
    // stage all 3 C tiles (24KB) then coalesced store
    #pragma unroll
    for (int z = 0; z < 3; ++z)
        #pragma unroll
        for (int t = 0; t < 2; ++t)
            #pragma unroll
            for (int u = 0; u < 2; ++u)
                #pragma unroll
                for (int r = 0; r < 4; ++r)
                    smem[z * 4096 + (wm + t * 16 + rb + r) * 64 + wn + u * 16 + fr] = f2bf(acc[z][t][u][r]);
    __syncthreads();
    unsigned short* O0s = (unsigned short*)O0;
    unsigned short* O1s = (unsigned short*)O1;
    unsigned short* O2s = (unsigned short*)O2;
    #pragma unroll
    for (int rep = 0; rep < 6; ++rep) {
        int idx = rep * 256 + tid;            // 1536 uint4 = 3 x 64 x 64 shorts
        int z = idx >> 9, rem = idx & 511;
        int row = rem >> 3, col8 = (rem & 7) * 8;
        unsigned short* Oz = (z == 0) ? O0s : ((z == 1) ? O1s : O2s);
        *(uint4*)(Oz + (size_t)(m0 + row) * 512 + n0 + col8) = *(const uint4*)&smem[z * 4096 + row * 64 + col8];
    }
}

// ---------------------------------------------------------------- per-chunk (64 rows) KV sums (bf16 out) + scaled V^T
// ScT[(n*32+c)][m*64+d] bf16 = sum_{j in chunk c} k[j][d]*v'[j][m], v' = v/|k_row|
// Vt_g[n][m][l] = v'[l][m] bf16.   Grid 512 = (n 16, c 32) -> 2 blocks/CU.
__global__ __launch_bounds__(256) void chunk_kv_kernel(
    const bf16* __restrict__ Kb, const bf16* __restrict__ Vb,
    const float* __restrict__ ssq, bf16* __restrict__ ScT, bf16* __restrict__ Vt_g)
{
    int n = blockIdx.x >> 5, c = blockIdx.x & 31;
    int b = n >> 3, h = n & 7;
    __shared__ float Ks[64 * 64];
    __shared__ float Vs[64 * 64];
    const unsigned short* Kg = (const unsigned short*)Kb;
    const unsigned short* Vg = (const unsigned short*)Vb;
    int tid = threadIdx.x;
    int td = tid >> 4, tm = tid & 15;
    int d0 = td * 4, m0 = tm * 4;
    #pragma unroll
    for (int rep = 0; rep < 4; ++rep) {
        int idx = rep * 1024 + tid * 4;
        int j = idx >> 6, d = idx & 63;
        int grow = (c * 64 + j) * 2 + b;
        ushort4 ku = *(const ushort4*)&Kg[(size_t)grow * 512 + h * 64 + d];
        ushort4 vu = *(const ushort4*)&Vg[(size_t)grow * 512 + h * 64 + d];
        float rk = 1.f / fmaxf(sqrtf(ssq[4096 + grow]), 1e-12f);
        *(float4*)&Ks[j * 64 + d] = make_float4(bf2f(ku.x), bf2f(ku.y), bf2f(ku.z), bf2f(ku.w));
        *(float4*)&Vs[j * 64 + d] = make_float4(bf2f(vu.x) * rk, bf2f(vu.y) * rk,
                                                bf2f(vu.z) * rk, bf2f(vu.w) * rk);
    }
    __syncthreads();
    float acc[4][4] = {};
    for (int j = 0; j < 64; ++j) {
        float4 kv = *(const float4*)&Ks[j * 64 + d0];
        float4 vv = *(const float4*)&Vs[j * 64 + m0];
        acc[0][0] += kv.x*vv.x; acc[0][1] += kv.x*vv.y; acc[0][2] += kv.x*vv.z; acc[0][3] += kv.x*vv.w;
        acc[1][0] += kv.y*vv.x; acc[1][1] += kv.y*vv.y; acc[1][2] += kv.y*vv.z; acc[1][3] += kv.y*vv.w;
        acc[2][0] += kv.z*vv.x; acc[2][1] += kv.z*vv.y; acc[2][2] += kv.z*vv.z; acc[2][3] += kv.z*vv.w;
        acc[3][0] += kv.w*vv.x; acc[3][1] += kv.w*vv.y; acc[3][2] += kv.w*vv.z; acc[3][3] += kv.w*vv.w;
    }
    // scaled V^T bf16: thread -> m = tid&63, 16 j's starting at (tid>>6)*16
    int vm = tid & 63, vj0 = (tid >> 6) * 16;
    unsigned short tmp[16];
    #pragma unroll
    for (int i = 0; i < 16; ++i) tmp[i] = f2bf(Vs[(vj0 + i) * 64 + vm]);
    size_t vtoff = (size_t)n * 131072 + (size_t)vm * 2048 + c * 64 + vj0;
    *(uint4*)((unsigned short*)Vt_g + vtoff)     = *(uint4*)&tmp[0];
    *(uint4*)((unsigned short*)Vt_g + vtoff + 8) = *(uint4*)&tmp[8];

    unsigned short* outp = (unsigned short*)ScT + (size_t)blockIdx.x * 4096;  // plane [m][d] bf16
    #pragma unroll
    for (int j2 = 0; j2 < 4; ++j2) {
        ushort4 o4;
        o4.x = f2bf(acc[0][j2]); o4.y = f2bf(acc[1][j2]);
        o4.z = f2bf(acc[2][j2]); o4.w = f2bf(acc[3][j2]);
        *(ushort4*)&outp[(m0 + j2) * 64 + d0] = o4;
    }
}

// ---------------------------------------------------------------- exclusive chunk prefix (32 planes) bf16->bf16
// 65536 threads, one (n, idx) column each; loads independent -> TLP hides L3 latency (R0/R1-proven pattern).
__global__ __launch_bounds__(256) void prefix_kernel(const bf16* __restrict__ ScT, bf16* __restrict__ SpT)
{
    int n = blockIdx.x >> 4;
    int idx = ((blockIdx.x & 15) << 8) + threadIdx.x;   // 0..4095 within plane
    size_t base = (size_t)n * 131072 + idx;
    const unsigned short* sc = (const unsigned short*)ScT;
    unsigned short* sp = (unsigned short*)SpT;
    float run = 0.f;
    #pragma unroll
    for (int c = 0; c < 32; ++c) {
        size_t off = base + (size_t)c * 4096;
        sp[off] = f2bf(run);
        run += bf2f(sc[off]);
    }
}

// ---------------------------------------------------------------- MFMA causal linear attention per (head, 64-chunk)
// out[l] = (1/|q_l|) * [ q_l @ Sprev + sum_{j<=l in chunk} (q_l . k_j) v'_j ].  Grid 512 -> 2 blocks/CU.
// Output written in PACKED layout for oproj: group g' = c*2+b, r = l, s = h*8..h*8+7.
__global__ __launch_bounds__(256) void attn_kernel(
    const bf16* __restrict__ Qb, const bf16* __restrict__ Kb,
    const bf16* __restrict__ Vt_g, const bf16* __restrict__ SpT_g,
    const float* __restrict__ ssq, bf16* __restrict__ AOb)
{
    int n = blockIdx.x >> 5, c = blockIdx.x & 31;
    int b = n >> 3, h = n & 7;
    __shared__ __align__(16) unsigned short Qs[64 * 72];   // [l][d]
    __shared__ __align__(16) unsigned short Ks[64 * 72];   // [j][d]
    __shared__ __align__(16) unsigned short Vt[64 * 72];   // [m][j]
    __shared__ __align__(16) unsigned short Ps[4 * 16 * 40];
    int tid = threadIdx.x;
    int lane = tid & 63;
    int w = tid >> 6;
    int fr = lane & 15, q = lane >> 4;

    const unsigned short* Qg = (const unsigned short*)Qb;
    const unsigned short* Kg = (const unsigned short*)Kb;
    const unsigned short* Vg = (const unsigned short*)Vt_g;

    #pragma unroll
    for (int rep = 0; rep < 2; ++rep) {
        int idx = rep * 256 + tid;
        int l = idx >> 3, dc = (idx & 7) * 8;
        size_t goff = (size_t)((c * 64 + l) * 2 + b) * 512 + h * 64 + dc;
        *(uint4*)&Qs[l * 72 + dc] = *(const uint4*)(Qg + goff);
        *(uint4*)&Ks[l * 72 + dc] = *(const uint4*)(Kg + goff);
        int m = l, jc = dc;
        *(uint4*)&Vt[m * 72 + jc] =
            *(const uint4*)(Vg + (size_t)n * 131072 + (size_t)m * 2048 + c * 64 + jc);
    }

    // rqv loads issued EARLY (before barrier + MFMA) so L2/L3 latency hides under compute (G7)
    int rbase = q * 4;
    float rqv[4];
    #pragma unroll
    for (int r = 0; r < 4; ++r) {
        int flat = (c * 64 + w * 16 + rbase + r) * 2 + b;
        rqv[r] = ssq[flat];
    }
    __syncthreads();

    short8 qfr[2];
    #pragma unroll
    for (int kh = 0; kh < 2; ++kh)
        qfr[kh] = *(const short8*)&Qs[(w * 16 + fr) * 72 + kh * 32 + q * 8];

    f32x4 zero4 = {0.f, 0.f, 0.f, 0.f};
    f32x4 oacc[4];
    #pragma unroll
    for (int mt = 0; mt < 4; ++mt) oacc[mt] = zero4;

    // O = Q @ Sprev^T (one 64x64 bf16 plane, L2/L3-hot)
    const unsigned short* spg = (const unsigned short*)SpT_g + (size_t)blockIdx.x * 4096;
    #pragma unroll
    for (int mt = 0; mt < 4; ++mt) {
        #pragma unroll
        for (int kh = 0; kh < 2; ++kh) {
            short8 sf = *(const short8*)&spg[(mt * 16 + fr) * 64 + kh * 32 + q * 8];
            oacc[mt] = __builtin_amdgcn_mfma_f32_16x16x32_bf16(qfr[kh], sf, oacc[mt], 0, 0, 0);
        }
    }

    unsigned short* myPs = &Ps[w * 640];      // 16 x 40
    int njt = (w >> 1) + 1;                   // 32-wide j-tiles needed by this wave
    for (int jt = 0; jt < njt; ++jt) {        // wave-uniform; barrier-free
        f32x4 pacc[2];
        pacc[0] = zero4; pacc[1] = zero4;
        #pragma unroll
        for (int jt16 = 0; jt16 < 2; ++jt16) {
            #pragma unroll
            for (int kh = 0; kh < 2; ++kh) {
                short8 kf = *(const short8*)&Ks[(jt * 32 + jt16 * 16 + fr) * 72 + kh * 32 + q * 8];
                pacc[jt16] = __builtin_amdgcn_mfma_f32_16x16x32_bf16(qfr[kh], kf, pacc[jt16], 0, 0, 0);
            }
        }
        bool diag = (jt == njt - 1);
        int lloc = w * 16 + rbase;            // + r
        #pragma unroll
        for (int jt16 = 0; jt16 < 2; ++jt16)
            #pragma unroll
            for (int r = 0; r < 4; ++r) {
                int jl = jt * 32 + jt16 * 16 + fr;
                float pv = pacc[jt16][r];
                if (diag && jl > lloc + r) pv = 0.f;
                myPs[(rbase + r) * 40 + jt16 * 16 + fr] = f2bf(pv);
            }
        short8 pf = *(const short8*)&myPs[fr * 40 + q * 8];
        #pragma unroll
        for (int mt = 0; mt < 4; ++mt) {
            short8 vf = *(const short8*)&Vt[(mt * 16 + fr) * 72 + jt * 32 + q * 8];
            oacc[mt] = __builtin_amdgcn_mfma_f32_16x16x32_bf16(pf, vf, oacc[mt], 0, 0, 0);
        }
    }

    // finalize 1/|q_l| from pre-loaded ssq values; stage, PACKED coalesced store
    #pragma unroll
    for (int r = 0; r < 4; ++r)
        rqv[r] = 1.f / fmaxf(sqrtf(rqv[r]), 1e-12f);
    __syncthreads();                          // Qs dead -> O staging [l][m] stride 64
    #pragma unroll
    for (int mt = 0; mt < 4; ++mt)
        #pragma unroll
        for (int r = 0; r < 4; ++r)
            Qs[(w * 16 + rbase + r) * 64 + mt * 16 + fr] = f2bf(oacc[mt][r] * rqv[r]);
    __syncthreads();
    // packed cell ((g'*64 + s)*64 + r)*8 with g' = c*2+b, r = l, s = h*8 + sl
    #pragma unroll
    for (int rep = 0; rep < 2; ++rep) {
        int idx8 = rep * 256 + tid;
        int sl = idx8 >> 6, l = idx8 & 63;
        *(uint4*)((unsigned short*)AOb +
                  (size_t)(((c * 2 + b) * 64 + h * 8 + sl) * 64 + l) * 8) =
            *(const uint4*)&Qs[l * 64 + sl * 8];
    }
}

// ---------------------------------------------------------------- output projection: 64x64 tile, grid (64,8)=512
// A (packed by attn) and W both staged via global_load_lds; BK=64 double-buffered 2-phase.
__global__ __launch_bounds__(256) void oproj_kernel(
    const bf16* __restrict__ A, const bf16* __restrict__ Wop,
    const float* __restrict__ bias, float* __restrict__ Out)
{
    // 32KB: 2 buffers x (As[8][64][8] + Bs[8][64][8]); epilogue Cf 64x64 f32 (16KB) reuses buf0
    __shared__ __align__(16) unsigned short smem[16384];
    const unsigned short* Ag = (const unsigned short*)A;
    const unsigned short* Wg = (const unsigned short*)Wop;
    int gp = blockIdx.x;              // packed A group
    int gy = blockIdx.y;
    int n0 = gy * 64;
    int tid = threadIdx.x;
    int lane = tid & 63;
    int w = tid >> 6;
    int fr = lane & 15, qf = lane >> 4;
    int wm = (w >> 1) * 32;
    int wn = (w & 1) * 32;

    f32x4 zero4 = {0.f, 0.f, 0.f, 0.f};
    f32x4 acc[2][2];
    acc[0][0] = zero4; acc[0][1] = zero4; acc[1][0] = zero4; acc[1][1] = zero4;

#define OPJ_STAGE(buf, it) do {                                                             \
        unsigned short* As_ = smem + (buf) * 8192;                                          \
        unsigned short* Bs_ = As_ + 4096;                                                   \
        int s0_ = (it) * 8;                                                                 \
        gl_lds16(Ag + ((size_t)(gp * 64 + s0_ + w * 2)     * 64 + lane) * 8, As_ + w * 1024);        \
        gl_lds16(Ag + ((size_t)(gp * 64 + s0_ + w * 2 + 1) * 64 + lane) * 8, As_ + w * 1024 + 512);  \
        gl_lds16(Wg + ((size_t)(gy * 64 + s0_ + w * 2)     * 64 + lane) * 8, Bs_ + w * 1024);        \
        gl_lds16(Wg + ((size_t)(gy * 64 + s0_ + w * 2 + 1) * 64 + lane) * 8, Bs_ + w * 1024 + 512);  \
    } while (0)

    int cur = 0;
    OPJ_STAGE(0, 0);
    __syncthreads();
    for (int it = 0; it < 8; ++it) {
        if (it < 7) OPJ_STAGE(cur ^ 1, it + 1);
        const unsigned short* As = smem + cur * 8192;
        const unsigned short* Bs = As + 4096;
        #pragma unroll
        for (int kk = 0; kk < 2; ++kk) {
            short8 af[2], bfx[2];
            #pragma unroll
            for (int t = 0; t < 2; ++t)
                af[t] = *(const short8*)&As[((kk * 4 + qf) * 64 + wm + t * 16 + fr) * 8];
            #pragma unroll
            for (int u = 0; u < 2; ++u)
                bfx[u] = *(const short8*)&Bs[((kk * 4 + qf) * 64 + wn + u * 16 + fr) * 8];
            #pragma unroll
            for (int t = 0; t < 2; ++t)
                #pragma unroll
                for (int u = 0; u < 2; ++u)
                    acc[t][u] = __builtin_amdgcn_mfma_f32_16x16x32_bf16(af[t], bfx[u], acc[t][u], 0, 0, 0);
        }
        __syncthreads();
        cur ^= 1;
    }
#undef OPJ_STAGE

    int rb = qf * 4;
    float* Cf = (float*)smem;          // 64 x 64 fp32 (final loop barrier already drained reads)
    #pragma unroll
    for (int t = 0; t < 2; ++t)
        #pragma unroll
        for (int u = 0; u < 2; ++u) {
            float bv = bias[n0 + wn + u * 16 + fr];
            #pragma unroll
            for (int r = 0; r < 4; ++r)
                Cf[(wm + t * 16 + rb + r) * 64 + wn + u * 16 + fr] = acc[t][u][r] + bv;
        }
    __syncthreads();
    int cbase = (gp >> 1) * 128, bb = gp & 1;
    #pragma unroll
    for (int rep = 0; rep < 4; ++rep) {
        int idx = rep * 256 + tid;
        int l2 = idx >> 4, c4 = (idx & 15) * 4;
        *(float4*)(Out + (size_t)(cbase + l2 * 2 + bb) * 512 + n0 + c4) = *(const float4*)&Cf[l2 * 64 + c4];
    }
}

// ---------------------------------------------------------------- launch (6 kernels)
extern "C" void kernel_launch(void* const* d_in, const int* in_sizes, int n_in,
                              void* d_out, int out_size, void* d_ws, size_t ws_size,
                              hipStream_t stream)
{
    (void)in_sizes; (void)n_in; (void)out_size; (void)ws_size;
    const float* x  = (const float*)d_in[0];
    const float* Wq = (const float*)d_in[1];
    const float* bq = (const float*)d_in[2];
    const float* Wk = (const float*)d_in[3];
    const float* bk = (const float*)d_in[4];
    const float* Wv = (const float*)d_in[5];
    const float* bv = (const float*)d_in[6];
    const float* Wo = (const float*)d_in[7];
    const float* bo = (const float*)d_in[8];
    float* out = (float*)d_out;

    float* ssq = (float*)d_ws;            // 8192 f32
    bf16* Xp  = (bf16*)(ssq + 8192);      // packed 4096x512
    bf16* Wqp = Xp + 2097152;             // packed 512x512 each
    bf16* Wkp = Wqp + 262144;
    bf16* Wvp = Wkp + 262144;
    bf16* Wop = Wvp + 262144;
    bf16* Qb  = Wop + 262144;             // row-major bf16 q/k/v
    bf16* Kb  = Qb + 2097152;
    bf16* Vb  = Kb + 2097152;
    bf16* Vt  = Vb + 2097152;             // 16*64*2048
    bf16* AOb = Vt + 2097152;             // PACKED attn output (g'=c*2+b, r=l)
    bf16* ScT = AOb + 2097152;            // 16*32*4096 bf16 chunk-sum planes [m][d]
    bf16* SpT = ScT + 2097152;            // 16*32*4096 bf16 exclusive-prefix planes

    pack_kernel<<<768, 256, 0, stream>>>(x, Wq, Wk, Wv, Wo, Xp, Wqp, Wkp, Wvp, Wop, ssq);
    qkv_gemm_kernel<<<dim3(64, 8), 256, 0, stream>>>(Xp, Wqp, Wkp, Wvp, bq, bk, bv, Qb, Kb, Vb, ssq);
    chunk_kv_kernel<<<dim3(512), 256, 0, stream>>>(Kb, Vb, ssq, ScT, Vt);
    prefix_kernel<<<dim3(256), 256, 0, stream>>>(ScT, SpT);
    attn_kernel<<<dim3(512), 256, 0, stream>>>(Qb, Kb, Vt, SpT, ssq, AOb);
    oproj_kernel<<<dim3(64, 8), 256, 0, stream>>>(AOb, Wop, bo, out);
}